// Round 1
// baseline (103.626 us; speedup 1.0000x reference)
//
#include <hip/hip_runtime.h>

#define NB   4
#define NT   8
#define NPTS 16384
#define NC   4
#define NK   16
// blocks in main kernel: NB*NPTS*NK/256 = 4096, of which 1024 per batch
#define NBLOCKS      4096
#define BLOCKS_PER_B 1024
#define GRAD_COUNT   8388608.0f   // T*N*K*C per batch

__global__ __launch_bounds__(256) void sobolev_main(
    const float4* __restrict__ pred,
    const float4* __restrict__ target,
    const int*    __restrict__ knn,
    const float*  __restrict__ pos,
    float*        __restrict__ part)
{
    const int tid = blockIdx.x * 256 + threadIdx.x;   // [0, B*N*K)
    const int k   = tid & (NK - 1);
    const int n   = (tid >> 4) & (NPTS - 1);
    const int b   = tid >> 18;
    const int j   = knn[tid];                          // flat (b,n,k) layout == tid

    // distance (inv_dist is constant over t,c -> factor out)
    const float* pc = pos + (b * NPTS + n) * 3;
    const float* pj = pos + (b * NPTS + j) * 3;
    const float dx = pj[0] - pc[0];
    const float dy = pj[1] - pc[1];
    const float dz = pj[2] - pc[2];
    const float d2   = fmaxf(dx*dx + dy*dy + dz*dz, 1e-8f);
    const float dist = fmaxf(sqrtf(d2), 1e-8f);
    const float inv_d = 1.0f / dist;

    float pg_abs = 0.f, tg_abs = 0.f, sd = 0.f, st = 0.f;
    const bool do_l2 = (k == 0);   // rl2 sums: cover each (b,t,n,c) exactly once

    #pragma unroll
    for (int t = 0; t < NT; ++t) {
        const int base = (b * NT + t) * NPTS;          // float4 index
        const float4 pcv = pred[base + n];
        const float4 pjv = pred[base + j];
        const float4 tcv = target[base + n];
        const float4 tjv = target[base + j];
        pg_abs += fabsf(pjv.x - pcv.x) + fabsf(pjv.y - pcv.y) +
                  fabsf(pjv.z - pcv.z) + fabsf(pjv.w - pcv.w);
        tg_abs += fabsf(tjv.x - tcv.x) + fabsf(tjv.y - tcv.y) +
                  fabsf(tjv.z - tcv.z) + fabsf(tjv.w - tcv.w);
        if (do_l2) {
            const float ex = pcv.x - tcv.x, ey = pcv.y - tcv.y;
            const float ez = pcv.z - tcv.z, ew = pcv.w - tcv.w;
            sd += ex*ex + ey*ey + ez*ez + ew*ew;
            st += tcv.x*tcv.x + tcv.y*tcv.y + tcv.z*tcv.z + tcv.w*tcv.w;
        }
    }

    float vals[4] = { pg_abs * inv_d, tg_abs * inv_d, sd, st };

    __shared__ float lds[4][4];
    const int wave = threadIdx.x >> 6;
    const int lane = threadIdx.x & 63;
    #pragma unroll
    for (int c = 0; c < 4; ++c) {
        float v = vals[c];
        #pragma unroll
        for (int o = 32; o > 0; o >>= 1) v += __shfl_down(v, o);
        if (lane == 0) lds[wave][c] = v;
    }
    __syncthreads();
    if (threadIdx.x < 4) {
        part[blockIdx.x * 4 + threadIdx.x] =
            lds[0][threadIdx.x] + lds[1][threadIdx.x] +
            lds[2][threadIdx.x] + lds[3][threadIdx.x];
    }
}

__global__ __launch_bounds__(256) void sobolev_finalize(
    const float* __restrict__ part, float* __restrict__ out)
{
    __shared__ float sums_s[16];   // [b][comp]
    __shared__ float lred[4];
    const int tid = threadIdx.x;

    for (int bc = 0; bc < 16; ++bc) {
        const int b = bc >> 2, comp = bc & 3;
        float s = 0.f;
        for (int i = tid; i < BLOCKS_PER_B; i += 256)
            s += part[(b * BLOCKS_PER_B + i) * 4 + comp];
        #pragma unroll
        for (int o = 32; o > 0; o >>= 1) s += __shfl_down(s, o);
        const int wave = tid >> 6, lane = tid & 63;
        if (lane == 0) lred[wave] = s;
        __syncthreads();
        if (tid == 0) sums_s[bc] = lred[0] + lred[1] + lred[2] + lred[3];
        __syncthreads();
    }

    if (tid == 0) {
        float rl2 = 0.f, ge = 0.f;
        const float inv_cnt = 1.0f / GRAD_COUNT;
        #pragma unroll
        for (int b = 0; b < NB; ++b) {
            const float pg = sums_s[b * 4 + 0] * inv_cnt;
            const float tg = sums_s[b * 4 + 1] * inv_cnt;
            const float sd = sums_s[b * 4 + 2];
            const float st = sums_s[b * 4 + 3];
            rl2 += sqrtf(sd) / fmaxf(sqrtf(st), 1e-8f);
            ge  += fabsf(pg - tg) / fmaxf(tg, 1e-8f);
        }
        out[0] = rl2 * 0.25f + 0.1f * (ge * 0.25f);
    }
}

extern "C" void kernel_launch(void* const* d_in, const int* in_sizes, int n_in,
                              void* d_out, int out_size, void* d_ws, size_t ws_size,
                              hipStream_t stream) {
    const float4* pred   = (const float4*)d_in[0];
    const float4* target = (const float4*)d_in[1];
    const int*    knn    = (const int*)d_in[2];
    const float*  pos    = (const float*)d_in[3];
    float* part = (float*)d_ws;          // 4096*4 floats = 64 KB
    float* out  = (float*)d_out;

    sobolev_main<<<NBLOCKS, 256, 0, stream>>>(pred, target, knn, pos, part);
    sobolev_finalize<<<1, 256, 0, stream>>>(part, out);
}

// Round 2
// 103.572 us; speedup vs baseline: 1.0005x; 1.0005x over previous
//
#include <hip/hip_runtime.h>

#define NB   4
#define NT   8
#define NPTS 16384
#define NC   4
#define NK   16
// Work split: 4 batches x 2 t-halves = 8 combos, one per XCD (blockIdx & 7).
// Per combo: N*K/256 = 1024 blocks -> grid 8192.
#define NBLOCKS      8192
#define SLOTS_PER_B  2048          // part slots per batch (2 combos x 1024)
#define GRAD_COUNT   8388608.0f    // T*N*K*C per batch

__global__ __launch_bounds__(256) void sobolev_main(
    const float4* __restrict__ pred,
    const float4* __restrict__ target,
    const int*    __restrict__ knn,
    const float*  __restrict__ pos,
    float*        __restrict__ part)
{
    // XCD-combo mapping: default dispatch round-robins blocks over 8 XCDs,
    // so blocks with equal (blockIdx&7) share an XCD/L2. Pin one
    // (batch, t-half) combo per XCD -> L2 working set ~3.2 MB < 4 MB.
    const int xcd   = blockIdx.x & 7;
    const int s     = blockIdx.x >> 3;          // 0..1023 within combo
    const int b     = xcd >> 1;
    const int thalf = xcd & 1;
    const int w     = s * 256 + threadIdx.x;    // [0, N*K)
    const int k     = w & (NK - 1);
    const int n     = w >> 4;
    const int j     = knn[(b << 18) + w];       // flat (b,n,k)

    const float* pc = pos + (b * NPTS + n) * 3;
    const float* pj = pos + (b * NPTS + j) * 3;
    const float dx = pj[0] - pc[0];
    const float dy = pj[1] - pc[1];
    const float dz = pj[2] - pc[2];
    const float d2   = fmaxf(dx*dx + dy*dy + dz*dz, 1e-8f);
    const float dist = fmaxf(sqrtf(d2), 1e-8f);
    const float inv_d = 1.0f / dist;

    float pg_abs = 0.f, tg_abs = 0.f, sd = 0.f, st = 0.f;
    const bool do_l2 = (k == 0);   // rl2 sums: each (b,t,n,c) exactly once

    const int t0 = thalf * 4;
    #pragma unroll
    for (int tt = 0; tt < 4; ++tt) {
        const int base = (b * NT + t0 + tt) * NPTS;   // float4 index
        const float4 pcv = pred[base + n];
        const float4 pjv = pred[base + j];
        const float4 tcv = target[base + n];
        const float4 tjv = target[base + j];
        pg_abs += fabsf(pjv.x - pcv.x) + fabsf(pjv.y - pcv.y) +
                  fabsf(pjv.z - pcv.z) + fabsf(pjv.w - pcv.w);
        tg_abs += fabsf(tjv.x - tcv.x) + fabsf(tjv.y - tcv.y) +
                  fabsf(tjv.z - tcv.z) + fabsf(tjv.w - tcv.w);
        if (do_l2) {
            const float ex = pcv.x - tcv.x, ey = pcv.y - tcv.y;
            const float ez = pcv.z - tcv.z, ew = pcv.w - tcv.w;
            sd += ex*ex + ey*ey + ez*ez + ew*ew;
            st += tcv.x*tcv.x + tcv.y*tcv.y + tcv.z*tcv.z + tcv.w*tcv.w;
        }
    }

    float vals[4] = { pg_abs * inv_d, tg_abs * inv_d, sd, st };

    __shared__ float lds[4][4];
    const int wave = threadIdx.x >> 6;
    const int lane = threadIdx.x & 63;
    #pragma unroll
    for (int c = 0; c < 4; ++c) {
        float v = vals[c];
        #pragma unroll
        for (int o = 32; o > 0; o >>= 1) v += __shfl_down(v, o);
        if (lane == 0) lds[wave][c] = v;
    }
    __syncthreads();
    if (threadIdx.x < 4) {
        // slot layout: batch-major so finalize sums contiguous ranges
        const int slot = (xcd << 10) | s;       // = b*2048 + thalf*1024 + s
        part[slot * 4 + threadIdx.x] =
            lds[0][threadIdx.x] + lds[1][threadIdx.x] +
            lds[2][threadIdx.x] + lds[3][threadIdx.x];
    }
}

__global__ __launch_bounds__(256) void sobolev_finalize(
    const float* __restrict__ part, float* __restrict__ out)
{
    __shared__ float sums_s[16];   // [b][comp]
    __shared__ float lred[4];
    const int tid = threadIdx.x;

    for (int bc = 0; bc < 16; ++bc) {
        const int b = bc >> 2, comp = bc & 3;
        float s = 0.f;
        for (int i = tid; i < SLOTS_PER_B; i += 256)
            s += part[(b * SLOTS_PER_B + i) * 4 + comp];
        #pragma unroll
        for (int o = 32; o > 0; o >>= 1) s += __shfl_down(s, o);
        const int wave = tid >> 6, lane = tid & 63;
        if (lane == 0) lred[wave] = s;
        __syncthreads();
        if (tid == 0) sums_s[bc] = lred[0] + lred[1] + lred[2] + lred[3];
        __syncthreads();
    }

    if (tid == 0) {
        float rl2 = 0.f, ge = 0.f;
        const float inv_cnt = 1.0f / GRAD_COUNT;
        #pragma unroll
        for (int b = 0; b < NB; ++b) {
            const float pg = sums_s[b * 4 + 0] * inv_cnt;
            const float tg = sums_s[b * 4 + 1] * inv_cnt;
            const float sd = sums_s[b * 4 + 2];
            const float st = sums_s[b * 4 + 3];
            rl2 += sqrtf(sd) / fmaxf(sqrtf(st), 1e-8f);
            ge  += fabsf(pg - tg) / fmaxf(tg, 1e-8f);
        }
        out[0] = rl2 * 0.25f + 0.1f * (ge * 0.25f);
    }
}

extern "C" void kernel_launch(void* const* d_in, const int* in_sizes, int n_in,
                              void* d_out, int out_size, void* d_ws, size_t ws_size,
                              hipStream_t stream) {
    const float4* pred   = (const float4*)d_in[0];
    const float4* target = (const float4*)d_in[1];
    const int*    knn    = (const int*)d_in[2];
    const float*  pos    = (const float*)d_in[3];
    float* part = (float*)d_ws;          // 8192*4 floats = 128 KB
    float* out  = (float*)d_out;

    sobolev_main<<<NBLOCKS, 256, 0, stream>>>(pred, target, knn, pos, part);
    sobolev_finalize<<<1, 256, 0, stream>>>(part, out);
}

// Round 3
// 47.171 us; speedup vs baseline: 2.1968x; 2.1957x over previous
//
#include <hip/hip_runtime.h>

#define NB   4
#define NT   8
#define NPTS 16384
#define NK   16
#define GRAD_COUNT 8388608.0f   // T*N*K*C per batch

// ---- packed-path workspace layout (bytes) ----
// P4    : [B][N][16] float4  = 16 MB   (chunk c: field=c>>3, t=c&7)
// pos4  : [B][N]     float4  =  1 MB
// partA : [B][4096][2] float = 128 KB  (grad partials, b-major)
// partB : [B][256][2]  float =   8 KB  (rl2 partials from pack kernel)
#define P4_ELEMS    (NB * NPTS * 16)
#define POS4_OFF    (P4_ELEMS)                 // in float4 units
#define PARTA_OFF_B (17825792)                 // byte offset of partA
#define PARTB_OFF_B (17825792 + 131072)
#define WS_NEEDED   (17825792 + 131072 + 8192)

// =================== packed path ===================

__global__ __launch_bounds__(256) void sobolev_pack(
    const float4* __restrict__ pred,
    const float4* __restrict__ target,
    const float*  __restrict__ pos,
    float4* __restrict__ P,        // [b][n][16]
    float4* __restrict__ pos4,     // [b][n]
    float*  __restrict__ partB)    // [b][256][2]
{
    const int blk = blockIdx.x;            // 1024 blocks, b-major
    const int b   = blk >> 8;
    const int n   = ((blk & 255) << 6) + (threadIdx.x >> 2);
    const int q   = threadIdx.x & 3;

    const float4 pv0 = pred  [(b * NT + q    ) * NPTS + n];
    const float4 pv1 = pred  [(b * NT + q + 4) * NPTS + n];
    const float4 tv0 = target[(b * NT + q    ) * NPTS + n];
    const float4 tv1 = target[(b * NT + q + 4) * NPTS + n];

    float4* blkp = P + (size_t)(b * NPTS + n) * 16;
    blkp[q]      = pv0;   // pred  t=q
    blkp[q + 4]  = pv1;   // pred  t=q+4
    blkp[q + 8]  = tv0;   // target t=q
    blkp[q + 12] = tv1;   // target t=q+4

    if (q == 0) {
        const float* pp = pos + (size_t)(b * NPTS + n) * 3;
        pos4[b * NPTS + n] = make_float4(pp[0], pp[1], pp[2], 0.f);
    }

    // rl2 partial sums (each (b,t,n,c) exactly once across lanes)
    float sd, st;
    {
        const float e0 = pv0.x - tv0.x, e1 = pv0.y - tv0.y,
                    e2 = pv0.z - tv0.z, e3 = pv0.w - tv0.w;
        const float f0 = pv1.x - tv1.x, f1 = pv1.y - tv1.y,
                    f2 = pv1.z - tv1.z, f3 = pv1.w - tv1.w;
        sd = e0*e0 + e1*e1 + e2*e2 + e3*e3 + f0*f0 + f1*f1 + f2*f2 + f3*f3;
        st = tv0.x*tv0.x + tv0.y*tv0.y + tv0.z*tv0.z + tv0.w*tv0.w +
             tv1.x*tv1.x + tv1.y*tv1.y + tv1.z*tv1.z + tv1.w*tv1.w;
    }

    __shared__ float lds[4][2];
    const int wave = threadIdx.x >> 6, lane = threadIdx.x & 63;
    #pragma unroll
    for (int o = 32; o > 0; o >>= 1) {
        sd += __shfl_down(sd, o);
        st += __shfl_down(st, o);
    }
    if (lane == 0) { lds[wave][0] = sd; lds[wave][1] = st; }
    __syncthreads();
    if (threadIdx.x < 2)
        partB[blk * 2 + threadIdx.x] =
            lds[0][threadIdx.x] + lds[1][threadIdx.x] +
            lds[2][threadIdx.x] + lds[3][threadIdx.x];
}

__global__ __launch_bounds__(256) void sobolev_grad(
    const float4* __restrict__ P,
    const float4* __restrict__ pos4,
    const int*    __restrict__ knn,
    float*        __restrict__ partA)   // [b][4096][2]
{
    // XCD pinning: b = (blockIdx&7)>>1 -> per-XCD set = P(b) 4MB + knn(b) 1MB
    const int xcd  = blockIdx.x & 7;
    const int b    = xcd >> 1;
    const int nblk = ((xcd & 1) << 11) | (blockIdx.x >> 3);   // 0..4095
    const int wave = threadIdx.x >> 6;
    const int lane = threadIdx.x & 63;
    const int k    = lane >> 2;       // 16 neighbor slots per wave
    const int q    = lane & 3;        // 4 lanes share one point-block
    const int n    = (nblk << 2) | wave;

    const int j = knn[(((b << 14) | n) << 4) | k];

    const float4* Bj = P + ((size_t)(b * NPTS + j) << 4);
    const float4* Bn = P + ((size_t)(b * NPTS + n) << 4);

    // instruction i: the 4 lanes of each group cover one full 64-B line
    const float4 gj0 = Bj[q];      const float4 gn0 = Bn[q];
    const float4 gj1 = Bj[q + 4];  const float4 gn1 = Bn[q + 4];
    const float4 gj2 = Bj[q + 8];  const float4 gn2 = Bn[q + 8];
    const float4 gj3 = Bj[q + 12]; const float4 gn3 = Bn[q + 12];

    const float4 pc = pos4[(b << 14) | n];
    const float4 pj = pos4[(b << 14) | j];
    const float dx = pj.x - pc.x, dy = pj.y - pc.y, dz = pj.z - pc.z;
    const float d2   = fmaxf(dx*dx + dy*dy + dz*dz, 1e-8f);
    const float dist = fmaxf(sqrtf(d2), 1e-8f);
    const float inv_d = 1.0f / dist;

    float pa =
        fabsf(gj0.x-gn0.x)+fabsf(gj0.y-gn0.y)+fabsf(gj0.z-gn0.z)+fabsf(gj0.w-gn0.w)+
        fabsf(gj1.x-gn1.x)+fabsf(gj1.y-gn1.y)+fabsf(gj1.z-gn1.z)+fabsf(gj1.w-gn1.w);
    float ta =
        fabsf(gj2.x-gn2.x)+fabsf(gj2.y-gn2.y)+fabsf(gj2.z-gn2.z)+fabsf(gj2.w-gn2.w)+
        fabsf(gj3.x-gn3.x)+fabsf(gj3.y-gn3.y)+fabsf(gj3.z-gn3.z)+fabsf(gj3.w-gn3.w);

    float v0 = pa * inv_d, v1 = ta * inv_d;

    __shared__ float lds[4][2];
    #pragma unroll
    for (int o = 32; o > 0; o >>= 1) {
        v0 += __shfl_down(v0, o);
        v1 += __shfl_down(v1, o);
    }
    if (lane == 0) { lds[wave][0] = v0; lds[wave][1] = v1; }
    __syncthreads();
    if (threadIdx.x < 2) {
        const int slot = (b << 12) | nblk;
        partA[slot * 2 + threadIdx.x] =
            lds[0][threadIdx.x] + lds[1][threadIdx.x] +
            lds[2][threadIdx.x] + lds[3][threadIdx.x];
    }
}

__global__ __launch_bounds__(256) void sobolev_final(
    const float* __restrict__ partA,   // [4][4096][2]
    const float* __restrict__ partB,   // [4][256][2]
    float*       __restrict__ out)
{
    const int tid = threadIdx.x;
    __shared__ float acc[NB][4];   // [b][{pg,tg,sd,st}]
    __shared__ float red[4][4];

    for (int b = 0; b < NB; ++b) {
        float pg = 0.f, tg = 0.f;
        const float2* pa2 = (const float2*)(partA + b * 4096 * 2);
        #pragma unroll
        for (int i = 0; i < 16; ++i) {
            const float2 v = pa2[i * 256 + tid];
            pg += v.x; tg += v.y;
        }
        const float2 vb = ((const float2*)(partB + b * 256 * 2))[tid];
        float sd = vb.x, st = vb.y;

        #pragma unroll
        for (int o = 32; o > 0; o >>= 1) {
            pg += __shfl_down(pg, o); tg += __shfl_down(tg, o);
            sd += __shfl_down(sd, o); st += __shfl_down(st, o);
        }
        const int wave = tid >> 6, lane = tid & 63;
        if (lane == 0) {
            red[wave][0] = pg; red[wave][1] = tg;
            red[wave][2] = sd; red[wave][3] = st;
        }
        __syncthreads();
        if (tid < 4)
            acc[b][tid] = red[0][tid] + red[1][tid] + red[2][tid] + red[3][tid];
        __syncthreads();
    }

    if (tid == 0) {
        float rl2 = 0.f, ge = 0.f;
        const float inv_cnt = 1.0f / GRAD_COUNT;
        #pragma unroll
        for (int b = 0; b < NB; ++b) {
            const float pg = acc[b][0] * inv_cnt;
            const float tg = acc[b][1] * inv_cnt;
            rl2 += sqrtf(acc[b][2]) / fmaxf(sqrtf(acc[b][3]), 1e-8f);
            ge  += fabsf(pg - tg) / fmaxf(tg, 1e-8f);
        }
        out[0] = rl2 * 0.25f + 0.1f * (ge * 0.25f);
    }
}

// =================== fallback path (R2 kernels, if ws too small) ===================

__global__ __launch_bounds__(256) void sobolev_main_fb(
    const float4* __restrict__ pred,
    const float4* __restrict__ target,
    const int*    __restrict__ knn,
    const float*  __restrict__ pos,
    float*        __restrict__ part)
{
    const int xcd   = blockIdx.x & 7;
    const int s     = blockIdx.x >> 3;
    const int b     = xcd >> 1;
    const int thalf = xcd & 1;
    const int w     = s * 256 + threadIdx.x;
    const int k     = w & (NK - 1);
    const int n     = w >> 4;
    const int j     = knn[(b << 18) + w];

    const float* pc = pos + (b * NPTS + n) * 3;
    const float* pj = pos + (b * NPTS + j) * 3;
    const float dx = pj[0] - pc[0], dy = pj[1] - pc[1], dz = pj[2] - pc[2];
    const float d2   = fmaxf(dx*dx + dy*dy + dz*dz, 1e-8f);
    const float dist = fmaxf(sqrtf(d2), 1e-8f);
    const float inv_d = 1.0f / dist;

    float pg_abs = 0.f, tg_abs = 0.f, sd = 0.f, st = 0.f;
    const bool do_l2 = (k == 0);
    const int t0 = thalf * 4;
    #pragma unroll
    for (int tt = 0; tt < 4; ++tt) {
        const int base = (b * NT + t0 + tt) * NPTS;
        const float4 pcv = pred[base + n];
        const float4 pjv = pred[base + j];
        const float4 tcv = target[base + n];
        const float4 tjv = target[base + j];
        pg_abs += fabsf(pjv.x-pcv.x)+fabsf(pjv.y-pcv.y)+fabsf(pjv.z-pcv.z)+fabsf(pjv.w-pcv.w);
        tg_abs += fabsf(tjv.x-tcv.x)+fabsf(tjv.y-tcv.y)+fabsf(tjv.z-tcv.z)+fabsf(tjv.w-tcv.w);
        if (do_l2) {
            const float ex = pcv.x-tcv.x, ey = pcv.y-tcv.y, ez = pcv.z-tcv.z, ew = pcv.w-tcv.w;
            sd += ex*ex + ey*ey + ez*ez + ew*ew;
            st += tcv.x*tcv.x + tcv.y*tcv.y + tcv.z*tcv.z + tcv.w*tcv.w;
        }
    }
    float vals[4] = { pg_abs * inv_d, tg_abs * inv_d, sd, st };
    __shared__ float lds[4][4];
    const int wave = threadIdx.x >> 6, lane = threadIdx.x & 63;
    #pragma unroll
    for (int c = 0; c < 4; ++c) {
        float v = vals[c];
        #pragma unroll
        for (int o = 32; o > 0; o >>= 1) v += __shfl_down(v, o);
        if (lane == 0) lds[wave][c] = v;
    }
    __syncthreads();
    if (threadIdx.x < 4) {
        const int slot = (xcd << 10) | s;
        part[slot * 4 + threadIdx.x] =
            lds[0][threadIdx.x] + lds[1][threadIdx.x] +
            lds[2][threadIdx.x] + lds[3][threadIdx.x];
    }
}

__global__ __launch_bounds__(256) void sobolev_finalize_fb(
    const float* __restrict__ part, float* __restrict__ out)
{
    __shared__ float sums_s[16];
    __shared__ float lred[4];
    const int tid = threadIdx.x;
    for (int bc = 0; bc < 16; ++bc) {
        const int b = bc >> 2, comp = bc & 3;
        float s = 0.f;
        for (int i = tid; i < 2048; i += 256)
            s += part[(b * 2048 + i) * 4 + comp];
        #pragma unroll
        for (int o = 32; o > 0; o >>= 1) s += __shfl_down(s, o);
        const int wave = tid >> 6, lane = tid & 63;
        if (lane == 0) lred[wave] = s;
        __syncthreads();
        if (tid == 0) sums_s[bc] = lred[0] + lred[1] + lred[2] + lred[3];
        __syncthreads();
    }
    if (tid == 0) {
        float rl2 = 0.f, ge = 0.f;
        const float inv_cnt = 1.0f / GRAD_COUNT;
        #pragma unroll
        for (int b = 0; b < NB; ++b) {
            const float pg = sums_s[b*4+0] * inv_cnt;
            const float tg = sums_s[b*4+1] * inv_cnt;
            rl2 += sqrtf(sums_s[b*4+2]) / fmaxf(sqrtf(sums_s[b*4+3]), 1e-8f);
            ge  += fabsf(pg - tg) / fmaxf(tg, 1e-8f);
        }
        out[0] = rl2 * 0.25f + 0.1f * (ge * 0.25f);
    }
}

// =================== launch ===================

extern "C" void kernel_launch(void* const* d_in, const int* in_sizes, int n_in,
                              void* d_out, int out_size, void* d_ws, size_t ws_size,
                              hipStream_t stream) {
    const float4* pred   = (const float4*)d_in[0];
    const float4* target = (const float4*)d_in[1];
    const int*    knn    = (const int*)d_in[2];
    const float*  pos    = (const float*)d_in[3];
    float* out = (float*)d_out;

    if (ws_size >= (size_t)WS_NEEDED) {
        float4* P4    = (float4*)d_ws;
        float4* pos4  = (float4*)d_ws + POS4_OFF;
        float*  partA = (float*)((char*)d_ws + PARTA_OFF_B);
        float*  partB = (float*)((char*)d_ws + PARTB_OFF_B);

        sobolev_pack<<<1024, 256, 0, stream>>>(pred, target, pos, P4, pos4, partB);
        sobolev_grad<<<16384, 256, 0, stream>>>(P4, pos4, knn, partA);
        sobolev_final<<<1, 256, 0, stream>>>(partA, partB, out);
    } else {
        float* part = (float*)d_ws;      // 8192*4 floats = 128 KB
        sobolev_main_fb<<<8192, 256, 0, stream>>>(pred, target, knn, pos, part);
        sobolev_finalize_fb<<<1, 256, 0, stream>>>(part, out);
    }
}

// Round 4
// 39.674 us; speedup vs baseline: 2.6120x; 1.1890x over previous
//
#include <hip/hip_runtime.h>
#include <hip/hip_fp16.h>

#define NB   4
#define NT   8
#define NPTS 16384
#define NK   16
#define GRAD_COUNT 8388608.0f   // T*N*K*C per batch

// ---- packed-path workspace layout (bytes) ----
// P     : [B][N][8] uint4 (fp16 fields) = 8 MB
//         chunk q in 0..3 : pred  t=2q,2q+1 (8 halves)
//         chunk 4+q       : target t=2q,2q+1
// pos4  : [B][N] float4   = 1 MB
// partA : [B][4096][2] f32 = 128 KB  (grad partials)
// partB : [B][256][2]  f32 =   8 KB  (rl2 partials)
#define P_BYTES     (NB * NPTS * 128)          // 8388608
#define POS4_OFF_B  P_BYTES
#define PARTA_OFF_B (P_BYTES + NB * NPTS * 16) // +1 MB
#define PARTB_OFF_B (PARTA_OFF_B + 131072)
#define WS_NEEDED   (PARTB_OFF_B + 8192)

__device__ __forceinline__ unsigned h2u(__half2 h) {
    return *reinterpret_cast<unsigned*>(&h);
}

__device__ __forceinline__ float absdiff8(const uint4& a, const uint4& b) {
    const __half2* ah = reinterpret_cast<const __half2*>(&a);
    const __half2* bh = reinterpret_cast<const __half2*>(&b);
    float s = 0.f;
    #pragma unroll
    for (int i = 0; i < 4; ++i) {
        const float2 f = __half22float2(__habs2(__hsub2(ah[i], bh[i])));
        s += f.x + f.y;
    }
    return s;
}

// =================== packed path ===================

__global__ __launch_bounds__(256) void sobolev_pack(
    const float4* __restrict__ pred,
    const float4* __restrict__ target,
    const float*  __restrict__ pos,
    uint4*  __restrict__ P,        // [b][n][8]
    float4* __restrict__ pos4,     // [b][n]
    float*  __restrict__ partB)    // [b][256][2]
{
    const int blk = blockIdx.x;            // 1024 blocks, b-major
    const int b   = blk >> 8;
    const int n   = ((blk & 255) << 6) + (threadIdx.x >> 2);
    const int q   = threadIdx.x & 3;       // lane q owns t = 2q, 2q+1

    const float4 pv0 = pred  [(b * NT + 2*q    ) * NPTS + n];
    const float4 pv1 = pred  [(b * NT + 2*q + 1) * NPTS + n];
    const float4 tv0 = target[(b * NT + 2*q    ) * NPTS + n];
    const float4 tv1 = target[(b * NT + 2*q + 1) * NPTS + n];

    uint4* blkp = P + (size_t)(b * NPTS + n) * 8;
    {
        uint4 cp, ct;
        cp.x = h2u(__float22half2_rn(make_float2(pv0.x, pv0.y)));
        cp.y = h2u(__float22half2_rn(make_float2(pv0.z, pv0.w)));
        cp.z = h2u(__float22half2_rn(make_float2(pv1.x, pv1.y)));
        cp.w = h2u(__float22half2_rn(make_float2(pv1.z, pv1.w)));
        ct.x = h2u(__float22half2_rn(make_float2(tv0.x, tv0.y)));
        ct.y = h2u(__float22half2_rn(make_float2(tv0.z, tv0.w)));
        ct.z = h2u(__float22half2_rn(make_float2(tv1.x, tv1.y)));
        ct.w = h2u(__float22half2_rn(make_float2(tv1.z, tv1.w)));
        blkp[q]     = cp;
        blkp[4 + q] = ct;
    }

    if (q == 0) {
        const float* pp = pos + (size_t)(b * NPTS + n) * 3;
        pos4[b * NPTS + n] = make_float4(pp[0], pp[1], pp[2], 0.f);
    }

    // rl2 partial sums in f32 (each (b,t,n,c) exactly once across lanes)
    float sd, st;
    {
        const float e0 = pv0.x - tv0.x, e1 = pv0.y - tv0.y,
                    e2 = pv0.z - tv0.z, e3 = pv0.w - tv0.w;
        const float f0 = pv1.x - tv1.x, f1 = pv1.y - tv1.y,
                    f2 = pv1.z - tv1.z, f3 = pv1.w - tv1.w;
        sd = e0*e0 + e1*e1 + e2*e2 + e3*e3 + f0*f0 + f1*f1 + f2*f2 + f3*f3;
        st = tv0.x*tv0.x + tv0.y*tv0.y + tv0.z*tv0.z + tv0.w*tv0.w +
             tv1.x*tv1.x + tv1.y*tv1.y + tv1.z*tv1.z + tv1.w*tv1.w;
    }

    __shared__ float lds[4][2];
    const int wave = threadIdx.x >> 6, lane = threadIdx.x & 63;
    #pragma unroll
    for (int o = 32; o > 0; o >>= 1) {
        sd += __shfl_down(sd, o);
        st += __shfl_down(st, o);
    }
    if (lane == 0) { lds[wave][0] = sd; lds[wave][1] = st; }
    __syncthreads();
    if (threadIdx.x < 2)
        partB[blk * 2 + threadIdx.x] =
            lds[0][threadIdx.x] + lds[1][threadIdx.x] +
            lds[2][threadIdx.x] + lds[3][threadIdx.x];
}

__global__ __launch_bounds__(256) void sobolev_grad(
    const uint4*  __restrict__ P,
    const float4* __restrict__ pos4,
    const int*    __restrict__ knn,
    float*        __restrict__ partA)   // [b][4096][2]
{
    // XCD pinning: per-XCD reused set = P(b) 2MB + pos4(b) 0.25MB (+ knn streamed)
    const int xcd  = blockIdx.x & 7;
    const int b    = xcd >> 1;
    const int nblk = ((xcd & 1) << 11) | (blockIdx.x >> 3);   // 0..4095
    const int wave = threadIdx.x >> 6;
    const int lane = threadIdx.x & 63;
    const int k    = lane >> 2;       // 16 neighbor slots per wave
    const int q    = lane & 3;        // 4 lanes share one point-block
    const int n    = (nblk << 2) | wave;

    const int j = knn[(((b << 14) | n) << 4) | k];

    const uint4* Bj = P + ((size_t)(b * NPTS + j) << 3);
    const uint4* Bn = P + ((size_t)(b * NPTS + n) << 3);

    // 2 gather instrs per tuple; each instr: 16 groups x 1 full 64-B line
    const uint4 gjp = Bj[q];      const uint4 gnp = Bn[q];
    const uint4 gjt = Bj[q + 4];  const uint4 gnt = Bn[q + 4];

    const float4 pc = pos4[(b << 14) | n];
    const float4 pj = pos4[(b << 14) | j];
    const float dx = pj.x - pc.x, dy = pj.y - pc.y, dz = pj.z - pc.z;
    const float d2   = fmaxf(dx*dx + dy*dy + dz*dz, 1e-8f);
    const float dist = fmaxf(sqrtf(d2), 1e-8f);
    const float inv_d = 1.0f / dist;

    float v0 = absdiff8(gjp, gnp) * inv_d;
    float v1 = absdiff8(gjt, gnt) * inv_d;

    __shared__ float lds[4][2];
    #pragma unroll
    for (int o = 32; o > 0; o >>= 1) {
        v0 += __shfl_down(v0, o);
        v1 += __shfl_down(v1, o);
    }
    if (lane == 0) { lds[wave][0] = v0; lds[wave][1] = v1; }
    __syncthreads();
    if (threadIdx.x < 2) {
        const int slot = (b << 12) | nblk;
        partA[slot * 2 + threadIdx.x] =
            lds[0][threadIdx.x] + lds[1][threadIdx.x] +
            lds[2][threadIdx.x] + lds[3][threadIdx.x];
    }
}

__global__ __launch_bounds__(256) void sobolev_final(
    const float* __restrict__ partA,   // [4][4096][2]
    const float* __restrict__ partB,   // [4][256][2]
    float*       __restrict__ out)
{
    const int tid = threadIdx.x;
    __shared__ float acc[NB][4];   // [b][{pg,tg,sd,st}]
    __shared__ float red[4][4];

    for (int b = 0; b < NB; ++b) {
        float pg = 0.f, tg = 0.f;
        const float2* pa2 = (const float2*)(partA + b * 4096 * 2);
        #pragma unroll
        for (int i = 0; i < 16; ++i) {
            const float2 v = pa2[i * 256 + tid];
            pg += v.x; tg += v.y;
        }
        const float2 vb = ((const float2*)(partB + b * 256 * 2))[tid];
        float sd = vb.x, st = vb.y;

        #pragma unroll
        for (int o = 32; o > 0; o >>= 1) {
            pg += __shfl_down(pg, o); tg += __shfl_down(tg, o);
            sd += __shfl_down(sd, o); st += __shfl_down(st, o);
        }
        const int wave = tid >> 6, lane = tid & 63;
        if (lane == 0) {
            red[wave][0] = pg; red[wave][1] = tg;
            red[wave][2] = sd; red[wave][3] = st;
        }
        __syncthreads();
        if (tid < 4)
            acc[b][tid] = red[0][tid] + red[1][tid] + red[2][tid] + red[3][tid];
        __syncthreads();
    }

    if (tid == 0) {
        float rl2 = 0.f, ge = 0.f;
        const float inv_cnt = 1.0f / GRAD_COUNT;
        #pragma unroll
        for (int b = 0; b < NB; ++b) {
            const float pg = acc[b][0] * inv_cnt;
            const float tg = acc[b][1] * inv_cnt;
            rl2 += sqrtf(acc[b][2]) / fmaxf(sqrtf(acc[b][3]), 1e-8f);
            ge  += fabsf(pg - tg) / fmaxf(tg, 1e-8f);
        }
        out[0] = rl2 * 0.25f + 0.1f * (ge * 0.25f);
    }
}

// =================== fallback path (if ws too small) ===================

__global__ __launch_bounds__(256) void sobolev_main_fb(
    const float4* __restrict__ pred,
    const float4* __restrict__ target,
    const int*    __restrict__ knn,
    const float*  __restrict__ pos,
    float*        __restrict__ part)
{
    const int xcd   = blockIdx.x & 7;
    const int s     = blockIdx.x >> 3;
    const int b     = xcd >> 1;
    const int thalf = xcd & 1;
    const int w     = s * 256 + threadIdx.x;
    const int k     = w & (NK - 1);
    const int n     = w >> 4;
    const int j     = knn[(b << 18) + w];

    const float* pc = pos + (b * NPTS + n) * 3;
    const float* pj = pos + (b * NPTS + j) * 3;
    const float dx = pj[0] - pc[0], dy = pj[1] - pc[1], dz = pj[2] - pc[2];
    const float d2   = fmaxf(dx*dx + dy*dy + dz*dz, 1e-8f);
    const float dist = fmaxf(sqrtf(d2), 1e-8f);
    const float inv_d = 1.0f / dist;

    float pg_abs = 0.f, tg_abs = 0.f, sd = 0.f, st = 0.f;
    const bool do_l2 = (k == 0);
    const int t0 = thalf * 4;
    #pragma unroll
    for (int tt = 0; tt < 4; ++tt) {
        const int base = (b * NT + t0 + tt) * NPTS;
        const float4 pcv = pred[base + n];
        const float4 pjv = pred[base + j];
        const float4 tcv = target[base + n];
        const float4 tjv = target[base + j];
        pg_abs += fabsf(pjv.x-pcv.x)+fabsf(pjv.y-pcv.y)+fabsf(pjv.z-pcv.z)+fabsf(pjv.w-pcv.w);
        tg_abs += fabsf(tjv.x-tcv.x)+fabsf(tjv.y-tcv.y)+fabsf(tjv.z-tcv.z)+fabsf(tjv.w-tcv.w);
        if (do_l2) {
            const float ex = pcv.x-tcv.x, ey = pcv.y-tcv.y, ez = pcv.z-tcv.z, ew = pcv.w-tcv.w;
            sd += ex*ex + ey*ey + ez*ez + ew*ew;
            st += tcv.x*tcv.x + tcv.y*tcv.y + tcv.z*tcv.z + tcv.w*tcv.w;
        }
    }
    float vals[4] = { pg_abs * inv_d, tg_abs * inv_d, sd, st };
    __shared__ float lds[4][4];
    const int wave = threadIdx.x >> 6, lane = threadIdx.x & 63;
    #pragma unroll
    for (int c = 0; c < 4; ++c) {
        float v = vals[c];
        #pragma unroll
        for (int o = 32; o > 0; o >>= 1) v += __shfl_down(v, o);
        if (lane == 0) lds[wave][c] = v;
    }
    __syncthreads();
    if (threadIdx.x < 4) {
        const int slot = (xcd << 10) | s;
        part[slot * 4 + threadIdx.x] =
            lds[0][threadIdx.x] + lds[1][threadIdx.x] +
            lds[2][threadIdx.x] + lds[3][threadIdx.x];
    }
}

__global__ __launch_bounds__(256) void sobolev_finalize_fb(
    const float* __restrict__ part, float* __restrict__ out)
{
    __shared__ float sums_s[16];
    __shared__ float lred[4];
    const int tid = threadIdx.x;
    for (int bc = 0; bc < 16; ++bc) {
        const int b = bc >> 2, comp = bc & 3;
        float s = 0.f;
        for (int i = tid; i < 2048; i += 256)
            s += part[(b * 2048 + i) * 4 + comp];
        #pragma unroll
        for (int o = 32; o > 0; o >>= 1) s += __shfl_down(s, o);
        const int wave = tid >> 6, lane = tid & 63;
        if (lane == 0) lred[wave] = s;
        __syncthreads();
        if (tid == 0) sums_s[bc] = lred[0] + lred[1] + lred[2] + lred[3];
        __syncthreads();
    }
    if (tid == 0) {
        float rl2 = 0.f, ge = 0.f;
        const float inv_cnt = 1.0f / GRAD_COUNT;
        #pragma unroll
        for (int b = 0; b < NB; ++b) {
            const float pg = sums_s[b*4+0] * inv_cnt;
            const float tg = sums_s[b*4+1] * inv_cnt;
            rl2 += sqrtf(sums_s[b*4+2]) / fmaxf(sqrtf(sums_s[b*4+3]), 1e-8f);
            ge  += fabsf(pg - tg) / fmaxf(tg, 1e-8f);
        }
        out[0] = rl2 * 0.25f + 0.1f * (ge * 0.25f);
    }
}

// =================== launch ===================

extern "C" void kernel_launch(void* const* d_in, const int* in_sizes, int n_in,
                              void* d_out, int out_size, void* d_ws, size_t ws_size,
                              hipStream_t stream) {
    const float4* pred   = (const float4*)d_in[0];
    const float4* target = (const float4*)d_in[1];
    const int*    knn    = (const int*)d_in[2];
    const float*  pos    = (const float*)d_in[3];
    float* out = (float*)d_out;

    if (ws_size >= (size_t)WS_NEEDED) {
        uint4*  P     = (uint4*)d_ws;
        float4* pos4  = (float4*)((char*)d_ws + POS4_OFF_B);
        float*  partA = (float*)((char*)d_ws + PARTA_OFF_B);
        float*  partB = (float*)((char*)d_ws + PARTB_OFF_B);

        sobolev_pack<<<1024, 256, 0, stream>>>(pred, target, pos, P, pos4, partB);
        sobolev_grad<<<16384, 256, 0, stream>>>(P, pos4, knn, partA);
        sobolev_final<<<1, 256, 0, stream>>>(partA, partB, out);
    } else {
        float* part = (float*)d_ws;      // 8192*4 floats = 128 KB
        sobolev_main_fb<<<8192, 256, 0, stream>>>(pred, target, knn, pos, part);
        sobolev_finalize_fb<<<1, 256, 0, stream>>>(part, out);
    }
}

// Round 5
// 35.634 us; speedup vs baseline: 2.9081x; 1.1134x over previous
//
#include <hip/hip_runtime.h>
#include <hip/hip_fp8.h>

#define NB   4
#define NT   8
#define NPTS 16384
#define NK   16
#define GRAD_COUNT 8388608.0f   // T*N*K*C per batch

// ---- packed-path workspace layout (bytes) ----
// P8    : [B][N][4] uint  x4  (fp8 fields, 64 B per point)          = 4 MB
//         chunk q (uint4): dword0 = pred t=q  c0..3
//                          dword1 = pred t=q+4
//                          dword2 = target t=q
//                          dword3 = target t=q+4
// pos4  : [B][N] float4                                             = 1 MB
// partA : [B][2048][2] f32 (grad partials)                          = 64 KB
// partB : [B][256][2]  f32 (rl2 partials)                           = 8 KB
#define P8_BYTES    (NB * NPTS * 64)           // 4 MB
#define POS4_OFF_B  P8_BYTES
#define PARTA_OFF_B (P8_BYTES + NB * NPTS * 16)
#define PARTB_OFF_B (PARTA_OFF_B + 65536)
#define WS_NEEDED   (PARTB_OFF_B + 8192)

#if defined(__has_builtin)
#if __has_builtin(__builtin_amdgcn_cvt_pk_f32_fp8) && __has_builtin(__builtin_amdgcn_cvt_pk_fp8_f32)
#define USE_FP8_BUILTINS 1
#endif
#endif

typedef float vf2 __attribute__((ext_vector_type(2)));

__device__ __forceinline__ unsigned pack4_fp8(float a, float b, float c, float d) {
#ifdef USE_FP8_BUILTINS
    int u = __builtin_amdgcn_cvt_pk_fp8_f32(a, b, 0, false);
    u     = __builtin_amdgcn_cvt_pk_fp8_f32(c, d, u, true);
    return (unsigned)u;
#else
    __hip_fp8_e4m3 ha(a), hb(b), hc(c), hd(d);
    return (unsigned)ha.__x | ((unsigned)hb.__x << 8) |
           ((unsigned)hc.__x << 16) | ((unsigned)hd.__x << 24);
#endif
}

// sum of |a_i - b_i| over 4 fp8 values packed in each dword
__device__ __forceinline__ float absdiff4(unsigned a, unsigned b) {
#ifdef USE_FP8_BUILTINS
    vf2 a0 = __builtin_amdgcn_cvt_pk_f32_fp8((int)a, false);
    vf2 a1 = __builtin_amdgcn_cvt_pk_f32_fp8((int)a, true);
    vf2 b0 = __builtin_amdgcn_cvt_pk_f32_fp8((int)b, false);
    vf2 b1 = __builtin_amdgcn_cvt_pk_f32_fp8((int)b, true);
    return fabsf(a0.x - b0.x) + fabsf(a0.y - b0.y) +
           fabsf(a1.x - b1.x) + fabsf(a1.y - b1.y);
#else
    float s = 0.f;
    #pragma unroll
    for (int i = 0; i < 4; ++i) {
        __hip_fp8_e4m3 ha, hb;
        ha.__x = (a >> (8 * i)) & 0xff;
        hb.__x = (b >> (8 * i)) & 0xff;
        s += fabsf((float)ha - (float)hb);
    }
    return s;
#endif
}

// =================== packed path ===================

__global__ __launch_bounds__(256) void sobolev_pack(
    const float4* __restrict__ pred,
    const float4* __restrict__ target,
    const float*  __restrict__ pos,
    uint4*  __restrict__ P,        // [b][n][4] chunks
    float4* __restrict__ pos4,     // [b][n]
    float*  __restrict__ partB)    // [b][256][2]
{
    const int blk = blockIdx.x;            // 1024 blocks, b-major
    const int b   = blk >> 8;
    const int n   = ((blk & 255) << 6) + (threadIdx.x >> 2);
    const int q   = threadIdx.x & 3;       // lane q owns t = q, q+4

    const float4 pv0 = pred  [(b * NT + q    ) * NPTS + n];
    const float4 pv1 = pred  [(b * NT + q + 4) * NPTS + n];
    const float4 tv0 = target[(b * NT + q    ) * NPTS + n];
    const float4 tv1 = target[(b * NT + q + 4) * NPTS + n];

    uint4 ck;
    ck.x = pack4_fp8(pv0.x, pv0.y, pv0.z, pv0.w);
    ck.y = pack4_fp8(pv1.x, pv1.y, pv1.z, pv1.w);
    ck.z = pack4_fp8(tv0.x, tv0.y, tv0.z, tv0.w);
    ck.w = pack4_fp8(tv1.x, tv1.y, tv1.z, tv1.w);
    P[((size_t)(b * NPTS + n) << 2) + q] = ck;

    if (q == 0) {
        const float* pp = pos + (size_t)(b * NPTS + n) * 3;
        pos4[b * NPTS + n] = make_float4(pp[0], pp[1], pp[2], 0.f);
    }

    // rl2 partial sums in f32 (each (b,t,n,c) exactly once across lanes)
    float sd, st;
    {
        const float e0 = pv0.x - tv0.x, e1 = pv0.y - tv0.y,
                    e2 = pv0.z - tv0.z, e3 = pv0.w - tv0.w;
        const float f0 = pv1.x - tv1.x, f1 = pv1.y - tv1.y,
                    f2 = pv1.z - tv1.z, f3 = pv1.w - tv1.w;
        sd = e0*e0 + e1*e1 + e2*e2 + e3*e3 + f0*f0 + f1*f1 + f2*f2 + f3*f3;
        st = tv0.x*tv0.x + tv0.y*tv0.y + tv0.z*tv0.z + tv0.w*tv0.w +
             tv1.x*tv1.x + tv1.y*tv1.y + tv1.z*tv1.z + tv1.w*tv1.w;
    }

    __shared__ float lds[4][2];
    const int wave = threadIdx.x >> 6, lane = threadIdx.x & 63;
    #pragma unroll
    for (int o = 32; o > 0; o >>= 1) {
        sd += __shfl_down(sd, o);
        st += __shfl_down(st, o);
    }
    if (lane == 0) { lds[wave][0] = sd; lds[wave][1] = st; }
    __syncthreads();
    if (threadIdx.x < 2)
        partB[blk * 2 + threadIdx.x] =
            lds[0][threadIdx.x] + lds[1][threadIdx.x] +
            lds[2][threadIdx.x] + lds[3][threadIdx.x];
}

__global__ __launch_bounds__(256) void sobolev_grad(
    const uint4*  __restrict__ P,
    const float4* __restrict__ pos4,
    const int*    __restrict__ knn,
    float*        __restrict__ partA)   // [b][2048][2]
{
    // XCD pinning: per-XCD reused set = P8(b) 1MB + pos4(b) 0.25MB + knn(b) streamed
    const int xcd  = blockIdx.x & 7;
    const int b    = xcd >> 1;
    const int nblk = ((xcd & 1) << 10) | (blockIdx.x >> 3);   // 0..2047
    const int wave = threadIdx.x >> 6;
    const int lane = threadIdx.x & 63;
    const int k    = lane >> 2;       // 16 neighbor slots per wave
    const int q    = lane & 3;        // 4 lanes share one point-block
    // two tuples per thread (2 n's per wave) for memory-level parallelism
    const int n0   = (nblk << 3) | (wave << 1);
    const int n1   = n0 | 1;

    const int j0 = knn[(((b << 14) | n0) << 4) | k];
    const int j1 = knn[(((b << 14) | n1) << 4) | k];

    const size_t pb = (size_t)(b * NPTS);
    const uint4 gj0 = P[((pb + j0) << 2) + q];
    const uint4 gn0 = P[((pb + n0) << 2) + q];
    const uint4 gj1 = P[((pb + j1) << 2) + q];
    const uint4 gn1 = P[((pb + n1) << 2) + q];

    const float4 pc0 = pos4[pb + n0];
    const float4 pj0 = pos4[pb + j0];
    const float4 pc1 = pos4[pb + n1];
    const float4 pj1 = pos4[pb + j1];

    const float dx0 = pj0.x - pc0.x, dy0 = pj0.y - pc0.y, dz0 = pj0.z - pc0.z;
    const float dx1 = pj1.x - pc1.x, dy1 = pj1.y - pc1.y, dz1 = pj1.z - pc1.z;
    const float d20 = fmaxf(dx0*dx0 + dy0*dy0 + dz0*dz0, 1e-8f);
    const float d21 = fmaxf(dx1*dx1 + dy1*dy1 + dz1*dz1, 1e-8f);
    const float inv_d0 = 1.0f / fmaxf(sqrtf(d20), 1e-8f);
    const float inv_d1 = 1.0f / fmaxf(sqrtf(d21), 1e-8f);

    // dwords x,y = pred (t=q, t=q+4); z,w = target
    const float sp0 = absdiff4(gj0.x, gn0.x) + absdiff4(gj0.y, gn0.y);
    const float st0 = absdiff4(gj0.z, gn0.z) + absdiff4(gj0.w, gn0.w);
    const float sp1 = absdiff4(gj1.x, gn1.x) + absdiff4(gj1.y, gn1.y);
    const float st1 = absdiff4(gj1.z, gn1.z) + absdiff4(gj1.w, gn1.w);

    float v0 = sp0 * inv_d0 + sp1 * inv_d1;   // pred grad partial
    float v1 = st0 * inv_d0 + st1 * inv_d1;   // target grad partial

    __shared__ float lds[4][2];
    #pragma unroll
    for (int o = 32; o > 0; o >>= 1) {
        v0 += __shfl_down(v0, o);
        v1 += __shfl_down(v1, o);
    }
    if (lane == 0) { lds[wave][0] = v0; lds[wave][1] = v1; }
    __syncthreads();
    if (threadIdx.x < 2) {
        const int slot = (b << 11) | nblk;
        partA[slot * 2 + threadIdx.x] =
            lds[0][threadIdx.x] + lds[1][threadIdx.x] +
            lds[2][threadIdx.x] + lds[3][threadIdx.x];
    }
}

__global__ __launch_bounds__(1024) void sobolev_final(
    const float* __restrict__ partA,   // [4][2048][2]
    const float* __restrict__ partB,   // [4][256][2]
    float*       __restrict__ out)
{
    const int tid = threadIdx.x;
    __shared__ float acc[NB][4];   // [b][{pg,tg,sd,st}]
    __shared__ float red[16][4];

    for (int b = 0; b < NB; ++b) {
        float pg = 0.f, tg = 0.f, sd = 0.f, st = 0.f;
        {
            const float2 v0 = ((const float2*)(partA + b * 2048 * 2))[tid & 2047];
            if (tid < 2048) { pg += v0.x; tg += v0.y; }   // tid 0..1023 covers half
            const float2 v1 = ((const float2*)(partA + b * 2048 * 2))[(tid & 2047) + 1024];
            if (tid < 1024) { pg += v1.x; tg += v1.y; }
        }
        if (tid < 256) {
            const float2 vb = ((const float2*)(partB + b * 256 * 2))[tid];
            sd = vb.x; st = vb.y;
        }
        #pragma unroll
        for (int o = 32; o > 0; o >>= 1) {
            pg += __shfl_down(pg, o); tg += __shfl_down(tg, o);
            sd += __shfl_down(sd, o); st += __shfl_down(st, o);
        }
        const int wave = tid >> 6, lane = tid & 63;
        if (lane == 0) {
            red[wave][0] = pg; red[wave][1] = tg;
            red[wave][2] = sd; red[wave][3] = st;
        }
        __syncthreads();
        if (tid < 4) {
            float s = 0.f;
            #pragma unroll
            for (int w = 0; w < 16; ++w) s += red[w][tid];
            acc[b][tid] = s;
        }
        __syncthreads();
    }

    if (tid == 0) {
        float rl2 = 0.f, ge = 0.f;
        const float inv_cnt = 1.0f / GRAD_COUNT;
        #pragma unroll
        for (int b = 0; b < NB; ++b) {
            const float pg = acc[b][0] * inv_cnt;
            const float tg = acc[b][1] * inv_cnt;
            rl2 += sqrtf(acc[b][2]) / fmaxf(sqrtf(acc[b][3]), 1e-8f);
            ge  += fabsf(pg - tg) / fmaxf(tg, 1e-8f);
        }
        out[0] = rl2 * 0.25f + 0.1f * (ge * 0.25f);
    }
}

// =================== fallback path (if ws too small) ===================

__global__ __launch_bounds__(256) void sobolev_main_fb(
    const float4* __restrict__ pred,
    const float4* __restrict__ target,
    const int*    __restrict__ knn,
    const float*  __restrict__ pos,
    float*        __restrict__ part)
{
    const int xcd   = blockIdx.x & 7;
    const int s     = blockIdx.x >> 3;
    const int b     = xcd >> 1;
    const int thalf = xcd & 1;
    const int w     = s * 256 + threadIdx.x;
    const int k     = w & (NK - 1);
    const int n     = w >> 4;
    const int j     = knn[(b << 18) + w];

    const float* pc = pos + (b * NPTS + n) * 3;
    const float* pj = pos + (b * NPTS + j) * 3;
    const float dx = pj[0] - pc[0], dy = pj[1] - pc[1], dz = pj[2] - pc[2];
    const float d2   = fmaxf(dx*dx + dy*dy + dz*dz, 1e-8f);
    const float dist = fmaxf(sqrtf(d2), 1e-8f);
    const float inv_d = 1.0f / dist;

    float pg_abs = 0.f, tg_abs = 0.f, sd = 0.f, st = 0.f;
    const bool do_l2 = (k == 0);
    const int t0 = thalf * 4;
    #pragma unroll
    for (int tt = 0; tt < 4; ++tt) {
        const int base = (b * NT + t0 + tt) * NPTS;
        const float4 pcv = pred[base + n];
        const float4 pjv = pred[base + j];
        const float4 tcv = target[base + n];
        const float4 tjv = target[base + j];
        pg_abs += fabsf(pjv.x-pcv.x)+fabsf(pjv.y-pcv.y)+fabsf(pjv.z-pcv.z)+fabsf(pjv.w-pcv.w);
        tg_abs += fabsf(tjv.x-tcv.x)+fabsf(tjv.y-tcv.y)+fabsf(tjv.z-tcv.z)+fabsf(tjv.w-tcv.w);
        if (do_l2) {
            const float ex = pcv.x-tcv.x, ey = pcv.y-tcv.y, ez = pcv.z-tcv.z, ew = pcv.w-tcv.w;
            sd += ex*ex + ey*ey + ez*ez + ew*ew;
            st += tcv.x*tcv.x + tcv.y*tcv.y + tcv.z*tcv.z + tcv.w*tcv.w;
        }
    }
    float vals[4] = { pg_abs * inv_d, tg_abs * inv_d, sd, st };
    __shared__ float lds[4][4];
    const int wave = threadIdx.x >> 6, lane = threadIdx.x & 63;
    #pragma unroll
    for (int c = 0; c < 4; ++c) {
        float v = vals[c];
        #pragma unroll
        for (int o = 32; o > 0; o >>= 1) v += __shfl_down(v, o);
        if (lane == 0) lds[wave][c] = v;
    }
    __syncthreads();
    if (threadIdx.x < 4) {
        const int slot = (xcd << 10) | s;
        part[slot * 4 + threadIdx.x] =
            lds[0][threadIdx.x] + lds[1][threadIdx.x] +
            lds[2][threadIdx.x] + lds[3][threadIdx.x];
    }
}

__global__ __launch_bounds__(256) void sobolev_finalize_fb(
    const float* __restrict__ part, float* __restrict__ out)
{
    __shared__ float sums_s[16];
    __shared__ float lred[4];
    const int tid = threadIdx.x;
    for (int bc = 0; bc < 16; ++bc) {
        const int b = bc >> 2, comp = bc & 3;
        float s = 0.f;
        for (int i = tid; i < 2048; i += 256)
            s += part[(b * 2048 + i) * 4 + comp];
        #pragma unroll
        for (int o = 32; o > 0; o >>= 1) s += __shfl_down(s, o);
        const int wave = tid >> 6, lane = tid & 63;
        if (lane == 0) lred[wave] = s;
        __syncthreads();
        if (tid == 0) sums_s[bc] = lred[0] + lred[1] + lred[2] + lred[3];
        __syncthreads();
    }
    if (tid == 0) {
        float rl2 = 0.f, ge = 0.f;
        const float inv_cnt = 1.0f / GRAD_COUNT;
        #pragma unroll
        for (int b = 0; b < NB; ++b) {
            const float pg = sums_s[b*4+0] * inv_cnt;
            const float tg = sums_s[b*4+1] * inv_cnt;
            rl2 += sqrtf(sums_s[b*4+2]) / fmaxf(sqrtf(sums_s[b*4+3]), 1e-8f);
            ge  += fabsf(pg - tg) / fmaxf(tg, 1e-8f);
        }
        out[0] = rl2 * 0.25f + 0.1f * (ge * 0.25f);
    }
}

// =================== launch ===================

extern "C" void kernel_launch(void* const* d_in, const int* in_sizes, int n_in,
                              void* d_out, int out_size, void* d_ws, size_t ws_size,
                              hipStream_t stream) {
    const float4* pred   = (const float4*)d_in[0];
    const float4* target = (const float4*)d_in[1];
    const int*    knn    = (const int*)d_in[2];
    const float*  pos    = (const float*)d_in[3];
    float* out = (float*)d_out;

    if (ws_size >= (size_t)WS_NEEDED) {
        uint4*  P     = (uint4*)d_ws;
        float4* pos4  = (float4*)((char*)d_ws + POS4_OFF_B);
        float*  partA = (float*)((char*)d_ws + PARTA_OFF_B);
        float*  partB = (float*)((char*)d_ws + PARTB_OFF_B);

        sobolev_pack<<<1024, 256, 0, stream>>>(pred, target, pos, P, pos4, partB);
        sobolev_grad<<<8192, 256, 0, stream>>>(P, pos4, knn, partA);
        sobolev_final<<<1, 1024, 0, stream>>>(partA, partB, out);
    } else {
        float* part = (float*)d_ws;      // 8192*4 floats = 128 KB
        sobolev_main_fb<<<8192, 256, 0, stream>>>(pred, target, knn, pos, part);
        sobolev_finalize_fb<<<1, 256, 0, stream>>>(part, out);
    }
}

// Round 6
// 35.566 us; speedup vs baseline: 2.9136x; 1.0019x over previous
//
#include <hip/hip_runtime.h>
#include <hip/hip_fp8.h>

#define NB   4
#define NT   8
#define NPTS 16384
#define NK   16
#define GRAD_COUNT 8388608.0f   // T*N*K*C per batch

// ---- packed-path workspace layout (bytes) ----
// P     : [B][N] 128-B point blocks                                 = 8 MB
//         uint4 c=0..3 : fp8 fields (dw0 pred t=q, dw1 pred t=q+4,
//                         dw2 target t=q, dw3 target t=q+4)
//         uint4 c=4    : f32 pos (x,y,z,pad)
//         c=5..7       : pad (never written / never read)
// partA : [B][2048][2] f32 (grad partials)                          = 64 KB
// partB : [B][256][2]  f32 (rl2 partials)                           = 8 KB
#define P_BYTES     (NB * NPTS * 128)          // 8 MB
#define PARTA_OFF_B P_BYTES
#define PARTB_OFF_B (PARTA_OFF_B + 65536)
#define WS_NEEDED   (PARTB_OFF_B + 8192)

#if defined(__has_builtin)
#if __has_builtin(__builtin_amdgcn_cvt_pk_f32_fp8) && __has_builtin(__builtin_amdgcn_cvt_pk_fp8_f32)
#define USE_FP8_BUILTINS 1
#endif
#endif

typedef float vf2 __attribute__((ext_vector_type(2)));

__device__ __forceinline__ unsigned pack4_fp8(float a, float b, float c, float d) {
#ifdef USE_FP8_BUILTINS
    int u = __builtin_amdgcn_cvt_pk_fp8_f32(a, b, 0, false);
    u     = __builtin_amdgcn_cvt_pk_fp8_f32(c, d, u, true);
    return (unsigned)u;
#else
    __hip_fp8_e4m3 ha(a), hb(b), hc(c), hd(d);
    return (unsigned)ha.__x | ((unsigned)hb.__x << 8) |
           ((unsigned)hc.__x << 16) | ((unsigned)hd.__x << 24);
#endif
}

// sum of |a_i - b_i| over 4 fp8 values packed in each dword
__device__ __forceinline__ float absdiff4(unsigned a, unsigned b) {
#ifdef USE_FP8_BUILTINS
    vf2 a0 = __builtin_amdgcn_cvt_pk_f32_fp8((int)a, false);
    vf2 a1 = __builtin_amdgcn_cvt_pk_f32_fp8((int)a, true);
    vf2 b0 = __builtin_amdgcn_cvt_pk_f32_fp8((int)b, false);
    vf2 b1 = __builtin_amdgcn_cvt_pk_f32_fp8((int)b, true);
    return fabsf(a0.x - b0.x) + fabsf(a0.y - b0.y) +
           fabsf(a1.x - b1.x) + fabsf(a1.y - b1.y);
#else
    float s = 0.f;
    #pragma unroll
    for (int i = 0; i < 4; ++i) {
        __hip_fp8_e4m3 ha, hb;
        ha.__x = (a >> (8 * i)) & 0xff;
        hb.__x = (b >> (8 * i)) & 0xff;
        s += fabsf((float)ha - (float)hb);
    }
    return s;
#endif
}

// =================== packed path ===================

__global__ __launch_bounds__(256) void sobolev_pack(
    const float4* __restrict__ pred,
    const float4* __restrict__ target,
    const float*  __restrict__ pos,
    uint4*  __restrict__ P,        // [b][n] blocks of 8 uint4 (128 B)
    float*  __restrict__ partB)    // [b][256][2]
{
    const int blk = blockIdx.x;            // 1024 blocks, b-major
    const int b   = blk >> 8;
    const int n   = ((blk & 255) << 6) + (threadIdx.x >> 2);
    const int q   = threadIdx.x & 3;       // lane q owns t = q, q+4

    const float4 pv0 = pred  [(b * NT + q    ) * NPTS + n];
    const float4 pv1 = pred  [(b * NT + q + 4) * NPTS + n];
    const float4 tv0 = target[(b * NT + q    ) * NPTS + n];
    const float4 tv1 = target[(b * NT + q + 4) * NPTS + n];

    uint4* blkp = P + ((size_t)(b * NPTS + n) << 3);
    {
        uint4 ck;
        ck.x = pack4_fp8(pv0.x, pv0.y, pv0.z, pv0.w);
        ck.y = pack4_fp8(pv1.x, pv1.y, pv1.z, pv1.w);
        ck.z = pack4_fp8(tv0.x, tv0.y, tv0.z, tv0.w);
        ck.w = pack4_fp8(tv1.x, tv1.y, tv1.z, tv1.w);
        blkp[q] = ck;
    }

    if (q == 0) {
        const float* pp = pos + (size_t)(b * NPTS + n) * 3;
        float4 p4 = make_float4(pp[0], pp[1], pp[2], 0.f);
        blkp[4] = *reinterpret_cast<const uint4*>(&p4);
    }

    // rl2 partial sums in f32 (each (b,t,n,c) exactly once across lanes)
    float sd, st;
    {
        const float e0 = pv0.x - tv0.x, e1 = pv0.y - tv0.y,
                    e2 = pv0.z - tv0.z, e3 = pv0.w - tv0.w;
        const float f0 = pv1.x - tv1.x, f1 = pv1.y - tv1.y,
                    f2 = pv1.z - tv1.z, f3 = pv1.w - tv1.w;
        sd = e0*e0 + e1*e1 + e2*e2 + e3*e3 + f0*f0 + f1*f1 + f2*f2 + f3*f3;
        st = tv0.x*tv0.x + tv0.y*tv0.y + tv0.z*tv0.z + tv0.w*tv0.w +
             tv1.x*tv1.x + tv1.y*tv1.y + tv1.z*tv1.z + tv1.w*tv1.w;
    }

    __shared__ float lds[4][2];
    const int wave = threadIdx.x >> 6, lane = threadIdx.x & 63;
    #pragma unroll
    for (int o = 32; o > 0; o >>= 1) {
        sd += __shfl_down(sd, o);
        st += __shfl_down(st, o);
    }
    if (lane == 0) { lds[wave][0] = sd; lds[wave][1] = st; }
    __syncthreads();
    if (threadIdx.x < 2)
        partB[blk * 2 + threadIdx.x] =
            lds[0][threadIdx.x] + lds[1][threadIdx.x] +
            lds[2][threadIdx.x] + lds[3][threadIdx.x];
}

__global__ __launch_bounds__(256) void sobolev_grad(
    const uint4*  __restrict__ P,
    const int*    __restrict__ knn,
    float*        __restrict__ partA)   // [b][2048][2]
{
    // XCD pinning: per-XCD reused set = P(b) 2MB + knn(b) streamed
    const int xcd  = blockIdx.x & 7;
    const int b    = xcd >> 1;
    const int nblk = ((xcd & 1) << 10) | (blockIdx.x >> 3);   // 0..2047
    const int wave = threadIdx.x >> 6;
    const int lane = threadIdx.x & 63;
    const int k    = lane >> 2;       // 16 neighbor slots per wave
    const int q    = lane & 3;        // 4 lanes share one point-block
    const int n0   = (nblk << 3) | (wave << 1);
    const int n1   = n0 | 1;

    const int j0 = knn[(((b << 14) | n0) << 4) | k];
    const int j1 = knn[(((b << 14) | n1) << 4) | k];

    const size_t pb = (size_t)(b * NPTS);
    const uint4* Bj0 = P + ((pb + j0) << 3);
    const uint4* Bn0 = P + ((pb + n0) << 3);
    const uint4* Bj1 = P + ((pb + j1) << 3);
    const uint4* Bn1 = P + ((pb + n1) << 3);

    // field chunk + pos live in the same 128-B block -> 1 region per j
    const uint4 gj0 = Bj0[q];
    const uint4 gn0 = Bn0[q];
    const uint4 gj1 = Bj1[q];
    const uint4 gn1 = Bn1[q];
    const float4 pj0 = *reinterpret_cast<const float4*>(Bj0 + 4);
    const float4 pc0 = *reinterpret_cast<const float4*>(Bn0 + 4);
    const float4 pj1 = *reinterpret_cast<const float4*>(Bj1 + 4);
    const float4 pc1 = *reinterpret_cast<const float4*>(Bn1 + 4);

    const float dx0 = pj0.x - pc0.x, dy0 = pj0.y - pc0.y, dz0 = pj0.z - pc0.z;
    const float dx1 = pj1.x - pc1.x, dy1 = pj1.y - pc1.y, dz1 = pj1.z - pc1.z;
    const float d20 = fmaxf(dx0*dx0 + dy0*dy0 + dz0*dz0, 1e-8f);
    const float d21 = fmaxf(dx1*dx1 + dy1*dy1 + dz1*dz1, 1e-8f);
    // d2 >= 1e-8 => sqrt(d2) >= 1e-4 > eps, so 1/max(sqrt,eps) == rsqrt(d2)
    const float inv_d0 = rsqrtf(d20);
    const float inv_d1 = rsqrtf(d21);

    // dwords x,y = pred (t=q, t=q+4); z,w = target
    const float sp0 = absdiff4(gj0.x, gn0.x) + absdiff4(gj0.y, gn0.y);
    const float st0 = absdiff4(gj0.z, gn0.z) + absdiff4(gj0.w, gn0.w);
    const float sp1 = absdiff4(gj1.x, gn1.x) + absdiff4(gj1.y, gn1.y);
    const float st1 = absdiff4(gj1.z, gn1.z) + absdiff4(gj1.w, gn1.w);

    float v0 = sp0 * inv_d0 + sp1 * inv_d1;   // pred grad partial
    float v1 = st0 * inv_d0 + st1 * inv_d1;   // target grad partial

    __shared__ float lds[4][2];
    #pragma unroll
    for (int o = 32; o > 0; o >>= 1) {
        v0 += __shfl_down(v0, o);
        v1 += __shfl_down(v1, o);
    }
    if (lane == 0) { lds[wave][0] = v0; lds[wave][1] = v1; }
    __syncthreads();
    if (threadIdx.x < 2) {
        const int slot = (b << 11) | nblk;
        partA[slot * 2 + threadIdx.x] =
            lds[0][threadIdx.x] + lds[1][threadIdx.x] +
            lds[2][threadIdx.x] + lds[3][threadIdx.x];
    }
}

__global__ __launch_bounds__(1024) void sobolev_final(
    const float* __restrict__ partA,   // [4][2048][2]
    const float* __restrict__ partB,   // [4][256][2]
    float*       __restrict__ out)
{
    const int tid = threadIdx.x;
    __shared__ float acc[NB][4];   // [b][{pg,tg,sd,st}]
    __shared__ float red[16][4];

    for (int b = 0; b < NB; ++b) {
        float pg = 0.f, tg = 0.f, sd = 0.f, st = 0.f;
        {
            const float2 v0 = ((const float2*)(partA + b * 2048 * 2))[tid];
            pg += v0.x; tg += v0.y;
            const float2 v1 = ((const float2*)(partA + b * 2048 * 2))[tid + 1024];
            pg += v1.x; tg += v1.y;
        }
        if (tid < 256) {
            const float2 vb = ((const float2*)(partB + b * 256 * 2))[tid];
            sd = vb.x; st = vb.y;
        }
        #pragma unroll
        for (int o = 32; o > 0; o >>= 1) {
            pg += __shfl_down(pg, o); tg += __shfl_down(tg, o);
            sd += __shfl_down(sd, o); st += __shfl_down(st, o);
        }
        const int wave = tid >> 6, lane = tid & 63;
        if (lane == 0) {
            red[wave][0] = pg; red[wave][1] = tg;
            red[wave][2] = sd; red[wave][3] = st;
        }
        __syncthreads();
        if (tid < 4) {
            float s = 0.f;
            #pragma unroll
            for (int w = 0; w < 16; ++w) s += red[w][tid];
            acc[b][tid] = s;
        }
        __syncthreads();
    }

    if (tid == 0) {
        float rl2 = 0.f, ge = 0.f;
        const float inv_cnt = 1.0f / GRAD_COUNT;
        #pragma unroll
        for (int b = 0; b < NB; ++b) {
            const float pg = acc[b][0] * inv_cnt;
            const float tg = acc[b][1] * inv_cnt;
            rl2 += sqrtf(acc[b][2]) / fmaxf(sqrtf(acc[b][3]), 1e-8f);
            ge  += fabsf(pg - tg) / fmaxf(tg, 1e-8f);
        }
        out[0] = rl2 * 0.25f + 0.1f * (ge * 0.25f);
    }
}

// =================== fallback path (if ws too small) ===================

__global__ __launch_bounds__(256) void sobolev_main_fb(
    const float4* __restrict__ pred,
    const float4* __restrict__ target,
    const int*    __restrict__ knn,
    const float*  __restrict__ pos,
    float*        __restrict__ part)
{
    const int xcd   = blockIdx.x & 7;
    const int s     = blockIdx.x >> 3;
    const int b     = xcd >> 1;
    const int thalf = xcd & 1;
    const int w     = s * 256 + threadIdx.x;
    const int k     = w & (NK - 1);
    const int n     = w >> 4;
    const int j     = knn[(b << 18) + w];

    const float* pc = pos + (b * NPTS + n) * 3;
    const float* pj = pos + (b * NPTS + j) * 3;
    const float dx = pj[0] - pc[0], dy = pj[1] - pc[1], dz = pj[2] - pc[2];
    const float d2   = fmaxf(dx*dx + dy*dy + dz*dz, 1e-8f);
    const float dist = fmaxf(sqrtf(d2), 1e-8f);
    const float inv_d = 1.0f / dist;

    float pg_abs = 0.f, tg_abs = 0.f, sd = 0.f, st = 0.f;
    const bool do_l2 = (k == 0);
    const int t0 = thalf * 4;
    #pragma unroll
    for (int tt = 0; tt < 4; ++tt) {
        const int base = (b * NT + t0 + tt) * NPTS;
        const float4 pcv = pred[base + n];
        const float4 pjv = pred[base + j];
        const float4 tcv = target[base + n];
        const float4 tjv = target[base + j];
        pg_abs += fabsf(pjv.x-pcv.x)+fabsf(pjv.y-pcv.y)+fabsf(pjv.z-pcv.z)+fabsf(pjv.w-pcv.w);
        tg_abs += fabsf(tjv.x-tcv.x)+fabsf(tjv.y-tcv.y)+fabsf(tjv.z-tcv.z)+fabsf(tjv.w-tcv.w);
        if (do_l2) {
            const float ex = pcv.x-tcv.x, ey = pcv.y-tcv.y, ez = pcv.z-tcv.z, ew = pcv.w-tcv.w;
            sd += ex*ex + ey*ey + ez*ez + ew*ew;
            st += tcv.x*tcv.x + tcv.y*tcv.y + tcv.z*tcv.z + tcv.w*tcv.w;
        }
    }
    float vals[4] = { pg_abs * inv_d, tg_abs * inv_d, sd, st };
    __shared__ float lds[4][4];
    const int wave = threadIdx.x >> 6, lane = threadIdx.x & 63;
    #pragma unroll
    for (int c = 0; c < 4; ++c) {
        float v = vals[c];
        #pragma unroll
        for (int o = 32; o > 0; o >>= 1) v += __shfl_down(v, o);
        if (lane == 0) lds[wave][c] = v;
    }
    __syncthreads();
    if (threadIdx.x < 4) {
        const int slot = (xcd << 10) | s;
        part[slot * 4 + threadIdx.x] =
            lds[0][threadIdx.x] + lds[1][threadIdx.x] +
            lds[2][threadIdx.x] + lds[3][threadIdx.x];
    }
}

__global__ __launch_bounds__(256) void sobolev_finalize_fb(
    const float* __restrict__ part, float* __restrict__ out)
{
    __shared__ float sums_s[16];
    __shared__ float lred[4];
    const int tid = threadIdx.x;
    for (int bc = 0; bc < 16; ++bc) {
        const int b = bc >> 2, comp = bc & 3;
        float s = 0.f;
        for (int i = tid; i < 2048; i += 256)
            s += part[(b * 2048 + i) * 4 + comp];
        #pragma unroll
        for (int o = 32; o > 0; o >>= 1) s += __shfl_down(s, o);
        const int wave = tid >> 6, lane = tid & 63;
        if (lane == 0) lred[wave] = s;
        __syncthreads();
        if (tid == 0) sums_s[bc] = lred[0] + lred[1] + lred[2] + lred[3];
        __syncthreads();
    }
    if (tid == 0) {
        float rl2 = 0.f, ge = 0.f;
        const float inv_cnt = 1.0f / GRAD_COUNT;
        #pragma unroll
        for (int b = 0; b < NB; ++b) {
            const float pg = sums_s[b*4+0] * inv_cnt;
            const float tg = sums_s[b*4+1] * inv_cnt;
            rl2 += sqrtf(sums_s[b*4+2]) / fmaxf(sqrtf(sums_s[b*4+3]), 1e-8f);
            ge  += fabsf(pg - tg) / fmaxf(tg, 1e-8f);
        }
        out[0] = rl2 * 0.25f + 0.1f * (ge * 0.25f);
    }
}

// =================== launch ===================

extern "C" void kernel_launch(void* const* d_in, const int* in_sizes, int n_in,
                              void* d_out, int out_size, void* d_ws, size_t ws_size,
                              hipStream_t stream) {
    const float4* pred   = (const float4*)d_in[0];
    const float4* target = (const float4*)d_in[1];
    const int*    knn    = (const int*)d_in[2];
    const float*  pos    = (const float*)d_in[3];
    float* out = (float*)d_out;

    if (ws_size >= (size_t)WS_NEEDED) {
        uint4*  P     = (uint4*)d_ws;
        float*  partA = (float*)((char*)d_ws + PARTA_OFF_B);
        float*  partB = (float*)((char*)d_ws + PARTB_OFF_B);

        sobolev_pack<<<1024, 256, 0, stream>>>(pred, target, pos, P, partB);
        sobolev_grad<<<8192, 256, 0, stream>>>(P, knn, partA);
        sobolev_final<<<1, 1024, 0, stream>>>(partA, partB, out);
    } else {
        float* part = (float*)d_ws;      // 8192*4 floats = 128 KB
        sobolev_main_fb<<<8192, 256, 0, stream>>>(pred, target, knn, pos, part);
        sobolev_finalize_fb<<<1, 256, 0, stream>>>(part, out);
    }
}